// Round 7
// baseline (505.671 us; speedup 1.0000x reference)
//
#include <hip/hip_runtime.h>

#define N_NODES 100000
#define D 128

typedef unsigned short ushort_t;
typedef unsigned char uchar_t;
typedef __attribute__((ext_vector_type(8))) short short8;
typedef __attribute__((ext_vector_type(4))) float f32x4;
typedef __attribute__((ext_vector_type(4))) int i32x4;

// round-to-nearest-even f32 -> bf16 bits (finite inputs)
__device__ __forceinline__ unsigned f2bf(float x) {
    unsigned u = __float_as_uint(x);
    return (u + 0x7fffu + ((u >> 16) & 1u)) >> 16;
}

// ---------------------------------------------------------------------------
// Kernel 1: W -> MFMA A-fragment-ordered bf16 (Wfrag).
// mfma_f32_16x16x32_bf16 A-frag: lane l holds row (l&15), k = (l>>4)*8+i.
// ---------------------------------------------------------------------------
__global__ __launch_bounds__(64)
void build_wfrag_kernel(const float* __restrict__ W,
                        ushort_t* __restrict__ Wfrag) {
    const int t  = blockIdx.x;      // 0..31 = jt*4 + kt
    const int jt = t >> 2, kt = t & 3;
    const int l  = threadIdx.x;
    const float* src = W + (size_t)(jt * 16 + (l & 15)) * D + kt * 32 + (l >> 4) * 8;
    const float4 p0 = *reinterpret_cast<const float4*>(src);
    const float4 p1 = *reinterpret_cast<const float4*>(src + 4);
    uint4 o;
    o.x = f2bf(p0.x) | (f2bf(p0.y) << 16);
    o.y = f2bf(p0.z) | (f2bf(p0.w) << 16);
    o.z = f2bf(p1.x) | (f2bf(p1.y) << 16);
    o.w = f2bf(p1.z) | (f2bf(p1.w) << 16);
    *reinterpret_cast<uint4*>(Wfrag + ((size_t)t * 64 + l) * 8) = o;
}

// ---------------------------------------------------------------------------
// Kernel 2: row_ptr by boundary detection on the SORTED edge_rows.
// row_ptr[i] = first e with rows[e] >= i. One coalesced sweep of rows[].
// ---------------------------------------------------------------------------
__global__ __launch_bounds__(256)
void build_rowptr_boundary_kernel(const int* __restrict__ rows,
                                  int* __restrict__ row_ptr, int n_edges) {
    const int e = blockIdx.x * 256 + threadIdx.x;
    if (e >= n_edges) return;
    const int r0 = rows[e];
    if (e == 0) {
        for (int r = 0; r <= r0; ++r) row_ptr[r] = 0;
    }
    if (e + 1 < n_edges) {
        const int r1 = rows[e + 1];
        for (int r = r0 + 1; r <= r1; ++r) row_ptr[r] = e + 1;
    } else {
        for (int r = r0 + 1; r <= N_NODES; ++r) row_ptr[r] = n_edges;
    }
}

// ---------------------------------------------------------------------------
// Degree counting sort: hist -> exclusive scan -> scatter to perm.
// Within-bucket atomic order varies, but all nodes in a bucket have EQUAL
// degree, and each node's output is computed identically -> deterministic out.
// ---------------------------------------------------------------------------
__global__ void hist_zero_kernel(int* __restrict__ hist) {
    hist[threadIdx.x] = 0;
}

__global__ __launch_bounds__(256)
void degree_hist_kernel(const int* __restrict__ row_ptr,
                        int* __restrict__ hist) {
    const int i = blockIdx.x * 256 + threadIdx.x;
    if (i >= N_NODES) return;
    int deg = row_ptr[i + 1] - row_ptr[i];
    deg = deg > 255 ? 255 : deg;
    atomicAdd(&hist[deg], 1);
}

__global__ __launch_bounds__(256)
void scan_hist_kernel(const int* __restrict__ hist, int* __restrict__ offs) {
    __shared__ int tmp[256];
    const int t = threadIdx.x;
    tmp[t] = hist[t];
    __syncthreads();
#pragma unroll
    for (int d = 1; d < 256; d <<= 1) {
        int v = (t >= d) ? tmp[t - d] : 0;
        __syncthreads();
        tmp[t] += v;
        __syncthreads();
    }
    offs[t] = (t == 0) ? 0 : tmp[t - 1];  // exclusive scan
}

__global__ __launch_bounds__(256)
void scatter_perm_kernel(const int* __restrict__ row_ptr,
                         int* __restrict__ offs, int* __restrict__ perm) {
    const int i = blockIdx.x * 256 + threadIdx.x;
    if (i >= N_NODES) return;
    int deg = row_ptr[i + 1] - row_ptr[i];
    deg = deg > 255 ? 255 : deg;
    const int slot = atomicAdd(&offs[deg], 1);
    perm[slot] = i;
}

// ---------------------------------------------------------------------------
// Kernel 3: G = H @ W^T via MFMA, quantized per-node to uint8 (+128 bias):
//   Gq[node][j] = round(g/s) + 128,  s = scales[node] = rowmax|g|/127.
// Row = 128 B = ONE cache line per edge in the gather.
// ---------------------------------------------------------------------------
__global__ __launch_bounds__(256)
void gemm_Gq_kernel(const float* __restrict__ h,
                    const ushort_t* __restrict__ Wfrag,
                    uchar_t* __restrict__ Gq,
                    float* __restrict__ scales) {
    const int wave = threadIdx.x >> 6;
    const int l    = threadIdx.x & 63;
    const int tile = blockIdx.x * 4 + wave;
    if (tile >= N_NODES / 16) return;
    const int n0   = tile * 16;
    const int lrow = l & 15;
    const int lk   = l >> 4;

    union { short8 v; ushort_t u[8]; } bfrag[4];
    const float* hp = h + (size_t)(n0 + lrow) * D + lk * 8;
#pragma unroll
    for (int kt = 0; kt < 4; ++kt) {
        const float4 q0 = *reinterpret_cast<const float4*>(hp + kt * 32);
        const float4 q1 = *reinterpret_cast<const float4*>(hp + kt * 32 + 4);
        bfrag[kt].u[0] = (ushort_t)f2bf(q0.x);
        bfrag[kt].u[1] = (ushort_t)f2bf(q0.y);
        bfrag[kt].u[2] = (ushort_t)f2bf(q0.z);
        bfrag[kt].u[3] = (ushort_t)f2bf(q0.w);
        bfrag[kt].u[4] = (ushort_t)f2bf(q1.x);
        bfrag[kt].u[5] = (ushort_t)f2bf(q1.y);
        bfrag[kt].u[6] = (ushort_t)f2bf(q1.z);
        bfrag[kt].u[7] = (ushort_t)f2bf(q1.w);
    }

    const uint4* wf = reinterpret_cast<const uint4*>(Wfrag) + l;
    f32x4 acc[8];
#pragma unroll
    for (int jt = 0; jt < 8; ++jt) {
        acc[jt] = (f32x4){0.f, 0.f, 0.f, 0.f};
#pragma unroll
        for (int kt = 0; kt < 4; ++kt) {
            union { uint4 q; short8 v; } af;
            af.q = wf[(jt * 4 + kt) * 64];
            acc[jt] = __builtin_amdgcn_mfma_f32_16x16x32_bf16(
                af.v, bfrag[kt].v, acc[jt], 0, 0, 0);
        }
    }

    float amax = 0.f;
#pragma unroll
    for (int jt = 0; jt < 8; ++jt) {
#pragma unroll
        for (int r = 0; r < 4; ++r) amax = fmaxf(amax, fabsf(acc[jt][r]));
    }
    amax = fmaxf(amax, __shfl_xor(amax, 16));
    amax = fmaxf(amax, __shfl_xor(amax, 32));
    const float s   = amax > 0.f ? amax * (1.f / 127.f) : 1.f;
    const float inv = amax > 0.f ? 127.f / amax : 0.f;

#pragma unroll
    for (int jt = 0; jt < 8; ++jt) {
        const unsigned q0 = (unsigned)((int)rintf(acc[jt][0] * inv) + 128);
        const unsigned q1 = (unsigned)((int)rintf(acc[jt][1] * inv) + 128);
        const unsigned q2 = (unsigned)((int)rintf(acc[jt][2] * inv) + 128);
        const unsigned q3 = (unsigned)((int)rintf(acc[jt][3] * inv) + 128);
        const unsigned pk = q0 | (q1 << 8) | (q2 << 16) | (q3 << 24);
        *reinterpret_cast<unsigned*>(
            Gq + (size_t)(n0 + lrow) * D + jt * 16 + lk * 4) = pk;
    }
    if (l < 16) scales[n0 + l] = s;
}

// ---------------------------------------------------------------------------
// Kernel 4: out = relu(S @ dequant(Gq) + b). One node per 16-lane group,
// nodes assigned via degree-sorted perm (wave's 4 groups have equal degree).
// Scale fused: vs = v * scales[c] (scales 400KB, L2-hot).
// Non-temporal cols/vals loads + out stores keep Gq resident in L2.
// ---------------------------------------------------------------------------
__device__ __forceinline__ void accq(float* a, float& vsum, float vs, uint2 g) {
    a[0] += vs * (float)(g.x & 0xffu);
    a[1] += vs * (float)((g.x >> 8) & 0xffu);
    a[2] += vs * (float)((g.x >> 16) & 0xffu);
    a[3] += vs * (float)(g.x >> 24);
    a[4] += vs * (float)(g.y & 0xffu);
    a[5] += vs * (float)((g.y >> 8) & 0xffu);
    a[6] += vs * (float)((g.y >> 16) & 0xffu);
    a[7] += vs * (float)(g.y >> 24);
    vsum += vs;
}

__global__ __launch_bounds__(256)
void gconv_gather_q2_kernel(const int* __restrict__ cols,
                            const float* __restrict__ vals,
                            const uchar_t* __restrict__ Gq,
                            const float* __restrict__ scales,
                            const float* __restrict__ bias,
                            const int* __restrict__ row_ptr,
                            const int* __restrict__ perm,
                            float* __restrict__ out) {
    const int tid  = blockIdx.x * 256 + threadIdx.x;
    const int il   = tid & 15;
    const int node = perm[tid >> 4];

    int e = row_ptr[node];
    const int end = row_ptr[node + 1];
    const uchar_t* gp = Gq + il * 8;

    float a[8];
#pragma unroll
    for (int j = 0; j < 8; ++j) a[j] = 0.f;
    float vsum = 0.f;

    // prologue: align e to 4 for vector cols/vals loads
    while (e < end && (e & 3)) {
        const int c = cols[e];
        const float vs = vals[e] * scales[c];
        const uint2 g = *reinterpret_cast<const uint2*>(gp + (size_t)c * D);
        accq(a, vsum, vs, g);
        ++e;
    }
    for (; e + 7 < end; e += 8) {
        const i32x4 ca = __builtin_nontemporal_load(
            reinterpret_cast<const i32x4*>(cols + e));
        const i32x4 cb = __builtin_nontemporal_load(
            reinterpret_cast<const i32x4*>(cols + e + 4));
        const f32x4 va = __builtin_nontemporal_load(
            reinterpret_cast<const f32x4*>(vals + e));
        const f32x4 vb = __builtin_nontemporal_load(
            reinterpret_cast<const f32x4*>(vals + e + 4));
        const int c[8] = {ca[0], ca[1], ca[2], ca[3], cb[0], cb[1], cb[2], cb[3]};
        const float v[8] = {va[0], va[1], va[2], va[3], vb[0], vb[1], vb[2], vb[3]};
        float s[8];
#pragma unroll
        for (int i = 0; i < 8; ++i) s[i] = scales[c[i]];
        uint2 g[8];
#pragma unroll
        for (int i = 0; i < 8; ++i)
            g[i] = *reinterpret_cast<const uint2*>(gp + (size_t)c[i] * D);
#pragma unroll
        for (int i = 0; i < 8; ++i) accq(a, vsum, v[i] * s[i], g[i]);
    }
    for (; e < end; ++e) {
        const int c = cols[e];
        const float vs = vals[e] * scales[c];
        const uint2 g = *reinterpret_cast<const uint2*>(gp + (size_t)c * D);
        accq(a, vsum, vs, g);
    }

    const float4 b0 = *reinterpret_cast<const float4*>(bias + il * 8);
    const float4 b1 = *reinterpret_cast<const float4*>(bias + il * 8 + 4);
    const float corr = 128.f * vsum;
    f32x4 r0, r1;
    r0[0] = a[0] - corr + b0.x; r0[1] = a[1] - corr + b0.y;
    r0[2] = a[2] - corr + b0.z; r0[3] = a[3] - corr + b0.w;
    r1[0] = a[4] - corr + b1.x; r1[1] = a[5] - corr + b1.y;
    r1[2] = a[6] - corr + b1.z; r1[3] = a[7] - corr + b1.w;
#pragma unroll
    for (int i = 0; i < 4; ++i) {
        r0[i] = r0[i] > 0.f ? r0[i] : 0.f;
        r1[i] = r1[i] > 0.f ? r1[i] : 0.f;
    }
    float* op = out + (size_t)node * D + il * 8;
    __builtin_nontemporal_store(r0, reinterpret_cast<f32x4*>(op));
    __builtin_nontemporal_store(r1, reinterpret_cast<f32x4*>(op + 4));
}

// ---------------------------------------------------------------------------
extern "C" void kernel_launch(void* const* d_in, const int* in_sizes, int n_in,
                              void* d_out, int out_size, void* d_ws,
                              size_t ws_size, hipStream_t stream) {
    const int*   edge_rows = (const int*)d_in[0];
    const int*   edge_cols = (const int*)d_in[1];
    const float* edge_vals = (const float*)d_in[2];
    const float* h         = (const float*)d_in[3];
    const float* W         = (const float*)d_in[4];
    const float* b         = (const float*)d_in[5];
    float*       out       = (float*)d_out;

    const int n_edges = in_sizes[0];

    // ws layout: [Wfrag 32K|pad64K][row_ptr 400K|pad512K][scales 400K|pad512K]
    //            [perm 400K|pad512K][hist 1K|pad4K][offs 1K|pad4K][Gq 12.8M]
    const size_t OFF_RP   = 64 * 1024;
    const size_t OFF_SC   = OFF_RP + 512 * 1024;
    const size_t OFF_PERM = OFF_SC + 512 * 1024;
    const size_t OFF_HIST = OFF_PERM + 512 * 1024;
    const size_t OFF_OFFS = OFF_HIST + 4 * 1024;
    const size_t OFF_GQ   = OFF_OFFS + 4 * 1024;

    ushort_t* Wfrag   = (ushort_t*)d_ws;
    int*      row_ptr = (int*)((char*)d_ws + OFF_RP);
    float*    scales  = (float*)((char*)d_ws + OFF_SC);
    int*      perm    = (int*)((char*)d_ws + OFF_PERM);
    int*      hist    = (int*)((char*)d_ws + OFF_HIST);
    int*      offs    = (int*)((char*)d_ws + OFF_OFFS);
    uchar_t*  Gq      = (uchar_t*)((char*)d_ws + OFF_GQ);

    build_wfrag_kernel<<<32, 64, 0, stream>>>(W, Wfrag);

    build_rowptr_boundary_kernel<<<(n_edges + 255) / 256, 256, 0, stream>>>(
        edge_rows, row_ptr, n_edges);

    const int nb_nodes = (N_NODES + 255) / 256;
    hist_zero_kernel<<<1, 256, 0, stream>>>(hist);
    degree_hist_kernel<<<nb_nodes, 256, 0, stream>>>(row_ptr, hist);
    scan_hist_kernel<<<1, 256, 0, stream>>>(hist, offs);
    scatter_perm_kernel<<<nb_nodes, 256, 0, stream>>>(row_ptr, offs, perm);

    const int n_tiles     = N_NODES / 16;  // 6250
    const int gemm_blocks = (n_tiles + 3) / 4;
    gemm_Gq_kernel<<<gemm_blocks, 256, 0, stream>>>(h, Wfrag, Gq, scales);

    const int gather_blocks = N_NODES * 16 / 256;  // 6250
    gconv_gather_q2_kernel<<<gather_blocks, 256, 0, stream>>>(
        edge_cols, edge_vals, Gq, scales, b, row_ptr, perm, out);
}

// Round 8
// 158.341 us; speedup vs baseline: 3.1936x; 3.1936x over previous
//
#include <hip/hip_runtime.h>

#define N_NODES 100000
#define D 128
#define NB_NODE_BLOCKS ((N_NODES + 255) / 256)

typedef unsigned short ushort_t;
typedef unsigned char uchar_t;
typedef __attribute__((ext_vector_type(8))) short short8;
typedef __attribute__((ext_vector_type(4))) float f32x4;
typedef __attribute__((ext_vector_type(4))) int i32x4;

// round-to-nearest-even f32 -> bf16 bits (finite inputs)
__device__ __forceinline__ unsigned f2bf(float x) {
    unsigned u = __float_as_uint(x);
    return (u + 0x7fffu + ((u >> 16) & 1u)) >> 16;
}

// ---------------------------------------------------------------------------
// Kernel 1: W -> MFMA A-fragment-ordered bf16 (Wfrag).
// mfma_f32_16x16x32_bf16 A-frag: lane l holds row (l&15), k = (l>>4)*8+i.
// ---------------------------------------------------------------------------
__global__ __launch_bounds__(64)
void build_wfrag_kernel(const float* __restrict__ W,
                        ushort_t* __restrict__ Wfrag) {
    const int t  = blockIdx.x;      // 0..31 = jt*4 + kt
    const int jt = t >> 2, kt = t & 3;
    const int l  = threadIdx.x;
    const float* src = W + (size_t)(jt * 16 + (l & 15)) * D + kt * 32 + (l >> 4) * 8;
    const float4 p0 = *reinterpret_cast<const float4*>(src);
    const float4 p1 = *reinterpret_cast<const float4*>(src + 4);
    uint4 o;
    o.x = f2bf(p0.x) | (f2bf(p0.y) << 16);
    o.y = f2bf(p0.z) | (f2bf(p0.w) << 16);
    o.z = f2bf(p1.x) | (f2bf(p1.y) << 16);
    o.w = f2bf(p1.z) | (f2bf(p1.w) << 16);
    *reinterpret_cast<uint4*>(Wfrag + ((size_t)t * 64 + l) * 8) = o;
}

// ---------------------------------------------------------------------------
// Kernel 2: row_ptr by boundary detection on the SORTED edge_rows.
// ---------------------------------------------------------------------------
__global__ __launch_bounds__(256)
void build_rowptr_boundary_kernel(const int* __restrict__ rows,
                                  int* __restrict__ row_ptr, int n_edges) {
    const int e = blockIdx.x * 256 + threadIdx.x;
    if (e >= n_edges) return;
    const int r0 = rows[e];
    if (e == 0) {
        for (int r = 0; r <= r0; ++r) row_ptr[r] = 0;
    }
    if (e + 1 < n_edges) {
        const int r1 = rows[e + 1];
        for (int r = r0 + 1; r <= r1; ++r) row_ptr[r] = e + 1;
    } else {
        for (int r = r0 + 1; r <= N_NODES; ++r) row_ptr[r] = n_edges;
    }
}

// ---------------------------------------------------------------------------
// Atomic-free stable counting sort of nodes by (clamped) degree.
// K1: per-block LDS hist -> blockHist[block][bin] (no global atomics).
// ---------------------------------------------------------------------------
__global__ __launch_bounds__(256)
void degree_hist_kernel(const int* __restrict__ row_ptr,
                        int* __restrict__ blockHist) {
    __shared__ int lh[256];
    lh[threadIdx.x] = 0;
    __syncthreads();
    const int i = blockIdx.x * 256 + threadIdx.x;
    if (i < N_NODES) {
        int deg = row_ptr[i + 1] - row_ptr[i];
        deg = deg > 255 ? 255 : deg;
        atomicAdd(&lh[deg], 1);  // LDS atomic only
    }
    __syncthreads();
    blockHist[(size_t)blockIdx.x * 256 + threadIdx.x] = lh[threadIdx.x];
}

// K2: one block. Thread t: serial exclusive scan of bin t across blocks
// (in place), then LDS scan across bins -> binStart.
__global__ __launch_bounds__(256)
void scan_blockhist_kernel(int* __restrict__ blockHist,
                           int* __restrict__ binStart) {
    const int t = threadIdx.x;
    int run = 0;
    for (int j = 0; j < NB_NODE_BLOCKS; ++j) {
        int* p = blockHist + (size_t)j * 256 + t;
        const int v = *p;
        *p = run;
        run += v;
    }
    __shared__ int tmp[256];
    tmp[t] = run;
    __syncthreads();
#pragma unroll
    for (int d = 1; d < 256; d <<= 1) {
        int v = (t >= d) ? tmp[t - d] : 0;
        __syncthreads();
        tmp[t] += v;
        __syncthreads();
    }
    binStart[t] = (t == 0) ? 0 : tmp[t - 1];  // exclusive over bins
}

// K3: scatter. Local rank via LDS atomic; global position is atomic-free.
__global__ __launch_bounds__(256)
void scatter_perm_kernel(const int* __restrict__ row_ptr,
                         const int* __restrict__ blockHist,
                         const int* __restrict__ binStart,
                         int* __restrict__ perm) {
    __shared__ int lh[256];
    lh[threadIdx.x] = 0;
    __syncthreads();
    const int i = blockIdx.x * 256 + threadIdx.x;
    int deg = 0, r = 0;
    const bool valid = i < N_NODES;
    if (valid) {
        deg = row_ptr[i + 1] - row_ptr[i];
        deg = deg > 255 ? 255 : deg;
        r = atomicAdd(&lh[deg], 1);  // LDS atomic only
    }
    __syncthreads();
    if (valid)
        perm[binStart[deg] + blockHist[(size_t)blockIdx.x * 256 + deg] + r] = i;
}

// ---------------------------------------------------------------------------
// Kernel 3: G = H @ W^T via MFMA, quantized per-node to uint8 (+128 bias):
//   Gq[node][j] = round(g/s) + 128,  s = scales[node] = rowmax|g|/127.
// Row = 128 B = ONE cache line per edge in the gather.
// ---------------------------------------------------------------------------
__global__ __launch_bounds__(256)
void gemm_Gq_kernel(const float* __restrict__ h,
                    const ushort_t* __restrict__ Wfrag,
                    uchar_t* __restrict__ Gq,
                    float* __restrict__ scales) {
    const int wave = threadIdx.x >> 6;
    const int l    = threadIdx.x & 63;
    const int tile = blockIdx.x * 4 + wave;
    if (tile >= N_NODES / 16) return;
    const int n0   = tile * 16;
    const int lrow = l & 15;
    const int lk   = l >> 4;

    union { short8 v; ushort_t u[8]; } bfrag[4];
    const float* hp = h + (size_t)(n0 + lrow) * D + lk * 8;
#pragma unroll
    for (int kt = 0; kt < 4; ++kt) {
        const float4 q0 = *reinterpret_cast<const float4*>(hp + kt * 32);
        const float4 q1 = *reinterpret_cast<const float4*>(hp + kt * 32 + 4);
        bfrag[kt].u[0] = (ushort_t)f2bf(q0.x);
        bfrag[kt].u[1] = (ushort_t)f2bf(q0.y);
        bfrag[kt].u[2] = (ushort_t)f2bf(q0.z);
        bfrag[kt].u[3] = (ushort_t)f2bf(q0.w);
        bfrag[kt].u[4] = (ushort_t)f2bf(q1.x);
        bfrag[kt].u[5] = (ushort_t)f2bf(q1.y);
        bfrag[kt].u[6] = (ushort_t)f2bf(q1.z);
        bfrag[kt].u[7] = (ushort_t)f2bf(q1.w);
    }

    const uint4* wf = reinterpret_cast<const uint4*>(Wfrag) + l;
    f32x4 acc[8];
#pragma unroll
    for (int jt = 0; jt < 8; ++jt) {
        acc[jt] = (f32x4){0.f, 0.f, 0.f, 0.f};
#pragma unroll
        for (int kt = 0; kt < 4; ++kt) {
            union { uint4 q; short8 v; } af;
            af.q = wf[(jt * 4 + kt) * 64];
            acc[jt] = __builtin_amdgcn_mfma_f32_16x16x32_bf16(
                af.v, bfrag[kt].v, acc[jt], 0, 0, 0);
        }
    }

    float amax = 0.f;
#pragma unroll
    for (int jt = 0; jt < 8; ++jt) {
#pragma unroll
        for (int r = 0; r < 4; ++r) amax = fmaxf(amax, fabsf(acc[jt][r]));
    }
    amax = fmaxf(amax, __shfl_xor(amax, 16));
    amax = fmaxf(amax, __shfl_xor(amax, 32));
    const float s   = amax > 0.f ? amax * (1.f / 127.f) : 1.f;
    const float inv = amax > 0.f ? 127.f / amax : 0.f;

#pragma unroll
    for (int jt = 0; jt < 8; ++jt) {
        const unsigned q0 = (unsigned)((int)rintf(acc[jt][0] * inv) + 128);
        const unsigned q1 = (unsigned)((int)rintf(acc[jt][1] * inv) + 128);
        const unsigned q2 = (unsigned)((int)rintf(acc[jt][2] * inv) + 128);
        const unsigned q3 = (unsigned)((int)rintf(acc[jt][3] * inv) + 128);
        const unsigned pk = q0 | (q1 << 8) | (q2 << 16) | (q3 << 24);
        *reinterpret_cast<unsigned*>(
            Gq + (size_t)(n0 + lrow) * D + jt * 16 + lk * 4) = pk;
    }
    if (l < 16) scales[n0 + l] = s;
}

// ---------------------------------------------------------------------------
// Kernel 4: out = relu(S @ dequant(Gq) + b). One node per 16-lane group,
// nodes assigned via degree-sorted perm (wave's 4 groups have equal degree).
// Scale fused: vs = v * scales[c] (scales 400KB, L2-hot).
// ---------------------------------------------------------------------------
__device__ __forceinline__ void accq(float* a, float& vsum, float vs, uint2 g) {
    a[0] += vs * (float)(g.x & 0xffu);
    a[1] += vs * (float)((g.x >> 8) & 0xffu);
    a[2] += vs * (float)((g.x >> 16) & 0xffu);
    a[3] += vs * (float)(g.x >> 24);
    a[4] += vs * (float)(g.y & 0xffu);
    a[5] += vs * (float)((g.y >> 8) & 0xffu);
    a[6] += vs * (float)((g.y >> 16) & 0xffu);
    a[7] += vs * (float)(g.y >> 24);
    vsum += vs;
}

__global__ __launch_bounds__(256)
void gconv_gather_q2_kernel(const int* __restrict__ cols,
                            const float* __restrict__ vals,
                            const uchar_t* __restrict__ Gq,
                            const float* __restrict__ scales,
                            const float* __restrict__ bias,
                            const int* __restrict__ row_ptr,
                            const int* __restrict__ perm,
                            float* __restrict__ out) {
    const int tid  = blockIdx.x * 256 + threadIdx.x;
    const int il   = tid & 15;
    const int node = perm[tid >> 4];

    int e = row_ptr[node];
    const int end = row_ptr[node + 1];
    const uchar_t* gp = Gq + il * 8;

    float a[8];
#pragma unroll
    for (int j = 0; j < 8; ++j) a[j] = 0.f;
    float vsum = 0.f;

    // prologue: align e to 4 for vector cols/vals loads
    while (e < end && (e & 3)) {
        const int c = cols[e];
        const float vs = vals[e] * scales[c];
        const uint2 g = *reinterpret_cast<const uint2*>(gp + (size_t)c * D);
        accq(a, vsum, vs, g);
        ++e;
    }
    for (; e + 7 < end; e += 8) {
        const i32x4 ca = __builtin_nontemporal_load(
            reinterpret_cast<const i32x4*>(cols + e));
        const i32x4 cb = __builtin_nontemporal_load(
            reinterpret_cast<const i32x4*>(cols + e + 4));
        const f32x4 va = __builtin_nontemporal_load(
            reinterpret_cast<const f32x4*>(vals + e));
        const f32x4 vb = __builtin_nontemporal_load(
            reinterpret_cast<const f32x4*>(vals + e + 4));
        const int c[8] = {ca[0], ca[1], ca[2], ca[3], cb[0], cb[1], cb[2], cb[3]};
        const float v[8] = {va[0], va[1], va[2], va[3], vb[0], vb[1], vb[2], vb[3]};
        float s[8];
#pragma unroll
        for (int i = 0; i < 8; ++i) s[i] = scales[c[i]];
        uint2 g[8];
#pragma unroll
        for (int i = 0; i < 8; ++i)
            g[i] = *reinterpret_cast<const uint2*>(gp + (size_t)c[i] * D);
#pragma unroll
        for (int i = 0; i < 8; ++i) accq(a, vsum, v[i] * s[i], g[i]);
    }
    for (; e < end; ++e) {
        const int c = cols[e];
        const float vs = vals[e] * scales[c];
        const uint2 g = *reinterpret_cast<const uint2*>(gp + (size_t)c * D);
        accq(a, vsum, vs, g);
    }

    const float4 b0 = *reinterpret_cast<const float4*>(bias + il * 8);
    const float4 b1 = *reinterpret_cast<const float4*>(bias + il * 8 + 4);
    const float corr = 128.f * vsum;
    f32x4 r0, r1;
    r0[0] = a[0] - corr + b0.x; r0[1] = a[1] - corr + b0.y;
    r0[2] = a[2] - corr + b0.z; r0[3] = a[3] - corr + b0.w;
    r1[0] = a[4] - corr + b1.x; r1[1] = a[5] - corr + b1.y;
    r1[2] = a[6] - corr + b1.z; r1[3] = a[7] - corr + b1.w;
#pragma unroll
    for (int i = 0; i < 4; ++i) {
        r0[i] = r0[i] > 0.f ? r0[i] : 0.f;
        r1[i] = r1[i] > 0.f ? r1[i] : 0.f;
    }
    float* op = out + (size_t)node * D + il * 8;
    __builtin_nontemporal_store(r0, reinterpret_cast<f32x4*>(op));
    __builtin_nontemporal_store(r1, reinterpret_cast<f32x4*>(op + 4));
}

// ---------------------------------------------------------------------------
extern "C" void kernel_launch(void* const* d_in, const int* in_sizes, int n_in,
                              void* d_out, int out_size, void* d_ws,
                              size_t ws_size, hipStream_t stream) {
    const int*   edge_rows = (const int*)d_in[0];
    const int*   edge_cols = (const int*)d_in[1];
    const float* edge_vals = (const float*)d_in[2];
    const float* h         = (const float*)d_in[3];
    const float* W         = (const float*)d_in[4];
    const float* b         = (const float*)d_in[5];
    float*       out       = (float*)d_out;

    const int n_edges = in_sizes[0];

    // ws layout: [Wfrag 32K|pad64K][row_ptr 400K|pad512K][scales 400K|pad512K]
    //            [perm 400K|pad512K][binStart 1K|pad4K][blockHist 400K|pad512K]
    //            [Gq 12.8M]
    const size_t OFF_RP   = 64 * 1024;
    const size_t OFF_SC   = OFF_RP + 512 * 1024;
    const size_t OFF_PERM = OFF_SC + 512 * 1024;
    const size_t OFF_BS   = OFF_PERM + 512 * 1024;
    const size_t OFF_BH   = OFF_BS + 4 * 1024;
    const size_t OFF_GQ   = OFF_BH + 512 * 1024;

    ushort_t* Wfrag     = (ushort_t*)d_ws;
    int*      row_ptr   = (int*)((char*)d_ws + OFF_RP);
    float*    scales    = (float*)((char*)d_ws + OFF_SC);
    int*      perm      = (int*)((char*)d_ws + OFF_PERM);
    int*      binStart  = (int*)((char*)d_ws + OFF_BS);
    int*      blockHist = (int*)((char*)d_ws + OFF_BH);
    uchar_t*  Gq        = (uchar_t*)((char*)d_ws + OFF_GQ);

    build_wfrag_kernel<<<32, 64, 0, stream>>>(W, Wfrag);

    build_rowptr_boundary_kernel<<<(n_edges + 255) / 256, 256, 0, stream>>>(
        edge_rows, row_ptr, n_edges);

    degree_hist_kernel<<<NB_NODE_BLOCKS, 256, 0, stream>>>(row_ptr, blockHist);
    scan_blockhist_kernel<<<1, 256, 0, stream>>>(blockHist, binStart);
    scatter_perm_kernel<<<NB_NODE_BLOCKS, 256, 0, stream>>>(row_ptr, blockHist,
                                                            binStart, perm);

    const int n_tiles     = N_NODES / 16;  // 6250
    const int gemm_blocks = (n_tiles + 3) / 4;
    gemm_Gq_kernel<<<gemm_blocks, 256, 0, stream>>>(h, Wfrag, Gq, scales);

    const int gather_blocks = N_NODES * 16 / 256;  // 6250
    gconv_gather_q2_kernel<<<gather_blocks, 256, 0, stream>>>(
        edge_cols, edge_vals, Gq, scales, b, row_ptr, perm, out);
}

// Round 9
// 131.746 us; speedup vs baseline: 3.8382x; 1.2019x over previous
//
#include <hip/hip_runtime.h>

#define N_NODES 100000
#define D 128
#define K_EDGES 256  // edges per 16-lane group (power of 2, 8-aligned chunks)

typedef unsigned short ushort_t;
typedef unsigned char uchar_t;
typedef __attribute__((ext_vector_type(8))) short short8;
typedef __attribute__((ext_vector_type(4))) float f32x4;
typedef __attribute__((ext_vector_type(4))) int i32x4;

// round-to-nearest-even f32 -> bf16 bits (finite inputs)
__device__ __forceinline__ unsigned f2bf(float x) {
    unsigned u = __float_as_uint(x);
    return (u + 0x7fffu + ((u >> 16) & 1u)) >> 16;
}

// ---------------------------------------------------------------------------
// Kernel 1: W -> MFMA A-fragment-ordered bf16 (Wfrag).
// ---------------------------------------------------------------------------
__global__ __launch_bounds__(64)
void build_wfrag_kernel(const float* __restrict__ W,
                        ushort_t* __restrict__ Wfrag) {
    const int t  = blockIdx.x;      // 0..31 = jt*4 + kt
    const int jt = t >> 2, kt = t & 3;
    const int l  = threadIdx.x;
    const float* src = W + (size_t)(jt * 16 + (l & 15)) * D + kt * 32 + (l >> 4) * 8;
    const float4 p0 = *reinterpret_cast<const float4*>(src);
    const float4 p1 = *reinterpret_cast<const float4*>(src + 4);
    uint4 o;
    o.x = f2bf(p0.x) | (f2bf(p0.y) << 16);
    o.y = f2bf(p0.z) | (f2bf(p0.w) << 16);
    o.z = f2bf(p1.x) | (f2bf(p1.y) << 16);
    o.w = f2bf(p1.z) | (f2bf(p1.w) << 16);
    *reinterpret_cast<uint4*>(Wfrag + ((size_t)t * 64 + l) * 8) = o;
}

// ---------------------------------------------------------------------------
// Kernel 2: row_ptr by boundary detection on the SORTED edge_rows.
// ---------------------------------------------------------------------------
__global__ __launch_bounds__(256)
void build_rowptr_boundary_kernel(const int* __restrict__ rows,
                                  int* __restrict__ row_ptr, int n_edges) {
    const int e = blockIdx.x * 256 + threadIdx.x;
    if (e >= n_edges) return;
    const int r0 = rows[e];
    if (e == 0) {
        for (int r = 0; r <= r0; ++r) row_ptr[r] = 0;
    }
    if (e + 1 < n_edges) {
        const int r1 = rows[e + 1];
        for (int r = r0 + 1; r <= r1; ++r) row_ptr[r] = e + 1;
    } else {
        for (int r = r0 + 1; r <= N_NODES; ++r) row_ptr[r] = n_edges;
    }
}

// ---------------------------------------------------------------------------
// Kernel 3: G = H @ W^T via MFMA, quantized per-node to uint8 (+128 bias):
//   Gq[node][j] = round(g/s) + 128, s = scales[node] = rowmax|g|/127.
// ---------------------------------------------------------------------------
__global__ __launch_bounds__(256)
void gemm_Gq_kernel(const float* __restrict__ h,
                    const ushort_t* __restrict__ Wfrag,
                    uchar_t* __restrict__ Gq,
                    float* __restrict__ scales) {
    const int wave = threadIdx.x >> 6;
    const int l    = threadIdx.x & 63;
    const int tile = blockIdx.x * 4 + wave;
    if (tile >= N_NODES / 16) return;
    const int n0   = tile * 16;
    const int lrow = l & 15;
    const int lk   = l >> 4;

    union { short8 v; ushort_t u[8]; } bfrag[4];
    const float* hp = h + (size_t)(n0 + lrow) * D + lk * 8;
#pragma unroll
    for (int kt = 0; kt < 4; ++kt) {
        const float4 q0 = *reinterpret_cast<const float4*>(hp + kt * 32);
        const float4 q1 = *reinterpret_cast<const float4*>(hp + kt * 32 + 4);
        bfrag[kt].u[0] = (ushort_t)f2bf(q0.x);
        bfrag[kt].u[1] = (ushort_t)f2bf(q0.y);
        bfrag[kt].u[2] = (ushort_t)f2bf(q0.z);
        bfrag[kt].u[3] = (ushort_t)f2bf(q0.w);
        bfrag[kt].u[4] = (ushort_t)f2bf(q1.x);
        bfrag[kt].u[5] = (ushort_t)f2bf(q1.y);
        bfrag[kt].u[6] = (ushort_t)f2bf(q1.z);
        bfrag[kt].u[7] = (ushort_t)f2bf(q1.w);
    }

    const uint4* wf = reinterpret_cast<const uint4*>(Wfrag) + l;
    f32x4 acc[8];
#pragma unroll
    for (int jt = 0; jt < 8; ++jt) {
        acc[jt] = (f32x4){0.f, 0.f, 0.f, 0.f};
#pragma unroll
        for (int kt = 0; kt < 4; ++kt) {
            union { uint4 q; short8 v; } af;
            af.q = wf[(jt * 4 + kt) * 64];
            acc[jt] = __builtin_amdgcn_mfma_f32_16x16x32_bf16(
                af.v, bfrag[kt].v, acc[jt], 0, 0, 0);
        }
    }

    float amax = 0.f;
#pragma unroll
    for (int jt = 0; jt < 8; ++jt) {
#pragma unroll
        for (int r = 0; r < 4; ++r) amax = fmaxf(amax, fabsf(acc[jt][r]));
    }
    amax = fmaxf(amax, __shfl_xor(amax, 16));
    amax = fmaxf(amax, __shfl_xor(amax, 32));
    const float s   = amax > 0.f ? amax * (1.f / 127.f) : 1.f;
    const float inv = amax > 0.f ? 127.f / amax : 0.f;

#pragma unroll
    for (int jt = 0; jt < 8; ++jt) {
        const unsigned q0 = (unsigned)((int)rintf(acc[jt][0] * inv) + 128);
        const unsigned q1 = (unsigned)((int)rintf(acc[jt][1] * inv) + 128);
        const unsigned q2 = (unsigned)((int)rintf(acc[jt][2] * inv) + 128);
        const unsigned q3 = (unsigned)((int)rintf(acc[jt][3] * inv) + 128);
        const unsigned pk = q0 | (q1 << 8) | (q2 << 16) | (q3 << 24);
        *reinterpret_cast<unsigned*>(
            Gq + (size_t)(n0 + lrow) * D + jt * 16 + lk * 4) = pk;
    }
    if (l < 16) scales[n0 + l] = s;
}

// ---------------------------------------------------------------------------
// Kernel 4: edge-balanced gather. Each 16-lane group owns edges
// [grp*K, grp*K+K) (contiguous). Interior row-runs -> out directly;
// boundary-clipped runs -> carryF/carryL[grp] (corrected partials, no bias).
// Both carry slots ALWAYS written (zeros if unused) -> no init, no atomics.
// ---------------------------------------------------------------------------
__device__ __forceinline__ void accq(float* a, float& vsum, float vs, uint2 g) {
    a[0] += vs * (float)(g.x & 0xffu);
    a[1] += vs * (float)((g.x >> 8) & 0xffu);
    a[2] += vs * (float)((g.x >> 16) & 0xffu);
    a[3] += vs * (float)(g.x >> 24);
    a[4] += vs * (float)(g.y & 0xffu);
    a[5] += vs * (float)((g.y >> 8) & 0xffu);
    a[6] += vs * (float)((g.y >> 16) & 0xffu);
    a[7] += vs * (float)(g.y >> 24);
    vsum += vs;
}

__device__ __forceinline__ void flush_run(
    int node, bool finalClipR, bool clippedL,
    bool& firstRun, bool& wroteF, bool& wroteL,
    float* a, float& vsum, int grp, int il,
    float* __restrict__ out, float* __restrict__ carryF,
    float* __restrict__ carryL, float4 b0, float4 b1) {
    const float corr = 128.f * vsum;
    const bool cL = firstRun && clippedL;
    if (cL || finalClipR) {
        float4 p0, p1;
        p0.x = a[0] - corr; p0.y = a[1] - corr;
        p0.z = a[2] - corr; p0.w = a[3] - corr;
        p1.x = a[4] - corr; p1.y = a[5] - corr;
        p1.z = a[6] - corr; p1.w = a[7] - corr;
        float* dst = (cL ? carryF : carryL) + (size_t)grp * 128 + il * 8;
        *reinterpret_cast<float4*>(dst)     = p0;
        *reinterpret_cast<float4*>(dst + 4) = p1;
        if (cL) wroteF = true; else wroteL = true;
    } else {
        f32x4 r0, r1;
        r0[0] = a[0] - corr + b0.x; r0[1] = a[1] - corr + b0.y;
        r0[2] = a[2] - corr + b0.z; r0[3] = a[3] - corr + b0.w;
        r1[0] = a[4] - corr + b1.x; r1[1] = a[5] - corr + b1.y;
        r1[2] = a[6] - corr + b1.z; r1[3] = a[7] - corr + b1.w;
#pragma unroll
        for (int i = 0; i < 4; ++i) {
            r0[i] = r0[i] > 0.f ? r0[i] : 0.f;
            r1[i] = r1[i] > 0.f ? r1[i] : 0.f;
        }
        float* op = out + (size_t)node * D + il * 8;
        *reinterpret_cast<f32x4*>(op)     = r0;
        *reinterpret_cast<f32x4*>(op + 4) = r1;
    }
    firstRun = false;
#pragma unroll
    for (int j = 0; j < 8; ++j) a[j] = 0.f;
    vsum = 0.f;
}

__global__ __launch_bounds__(256)
void gconv_gather_eb_kernel(const int* __restrict__ rows,
                            const int* __restrict__ cols,
                            const float* __restrict__ vals,
                            const uchar_t* __restrict__ Gq,
                            const float* __restrict__ scales,
                            const float* __restrict__ bias,
                            float* __restrict__ out,
                            float* __restrict__ carryF,
                            float* __restrict__ carryL,
                            int n_edges, int n_groups) {
    const int tid = blockIdx.x * 256 + threadIdx.x;
    const int grp = tid >> 4;
    const int il  = tid & 15;
    if (grp >= n_groups) return;

    const int e0 = grp * K_EDGES;
    const int e1 = min(n_edges, e0 + K_EDGES);
    const uchar_t* gp = Gq + il * 8;
    const float4 b0 = *reinterpret_cast<const float4*>(bias + il * 8);
    const float4 b1 = *reinterpret_cast<const float4*>(bias + il * 8 + 4);

    int cur = rows[e0];
    const bool clippedL = (grp > 0) && (rows[e0 - 1] == cur);
    bool firstRun = true, wroteF = false, wroteL = false;

    float a[8];
#pragma unroll
    for (int j = 0; j < 8; ++j) a[j] = 0.f;
    float vsum = 0.f;

    int e = e0;
    for (; e + 8 <= e1; e += 8) {
        const i32x4 ra = *reinterpret_cast<const i32x4*>(rows + e);
        const i32x4 rb = *reinterpret_cast<const i32x4*>(rows + e + 4);
        const i32x4 ca = *reinterpret_cast<const i32x4*>(cols + e);
        const i32x4 cb = *reinterpret_cast<const i32x4*>(cols + e + 4);
        const f32x4 va = *reinterpret_cast<const f32x4*>(vals + e);
        const f32x4 vb = *reinterpret_cast<const f32x4*>(vals + e + 4);
        const int r[8] = {ra[0], ra[1], ra[2], ra[3], rb[0], rb[1], rb[2], rb[3]};
        const int c[8] = {ca[0], ca[1], ca[2], ca[3], cb[0], cb[1], cb[2], cb[3]};
        const float v[8] = {va[0], va[1], va[2], va[3], vb[0], vb[1], vb[2], vb[3]};
        float s[8];
#pragma unroll
        for (int i = 0; i < 8; ++i) s[i] = scales[c[i]];
        uint2 g[8];
#pragma unroll
        for (int i = 0; i < 8; ++i)
            g[i] = *reinterpret_cast<const uint2*>(gp + (size_t)c[i] * D);
#pragma unroll
        for (int i = 0; i < 8; ++i) {
            if (r[i] != cur) {
                flush_run(cur, false, clippedL, firstRun, wroteF, wroteL,
                          a, vsum, grp, il, out, carryF, carryL, b0, b1);
                cur = r[i];
            }
            accq(a, vsum, v[i] * s[i], g[i]);
        }
    }
    for (; e < e1; ++e) {  // tail (last group only)
        const int r_ = rows[e];
        const int c_ = cols[e];
        if (r_ != cur) {
            flush_run(cur, false, clippedL, firstRun, wroteF, wroteL,
                      a, vsum, grp, il, out, carryF, carryL, b0, b1);
            cur = r_;
        }
        const uint2 g_ = *reinterpret_cast<const uint2*>(gp + (size_t)c_ * D);
        accq(a, vsum, vals[e] * scales[c_], g_);
    }

    const bool clipR = (e1 < n_edges) && (rows[e1] == cur);
    flush_run(cur, clipR, clippedL, firstRun, wroteF, wroteL,
              a, vsum, grp, il, out, carryF, carryL, b0, b1);

    const f32x4 z = {0.f, 0.f, 0.f, 0.f};
    if (!wroteF) {
        float* dst = carryF + (size_t)grp * 128 + il * 8;
        *reinterpret_cast<f32x4*>(dst)     = z;
        *reinterpret_cast<f32x4*>(dst + 4) = z;
    }
    if (!wroteL) {
        float* dst = carryL + (size_t)grp * 128 + il * 8;
        *reinterpret_cast<f32x4*>(dst)     = z;
        *reinterpret_cast<f32x4*>(dst + 4) = z;
    }
}

// ---------------------------------------------------------------------------
// Kernel 5: fixup. Boundary-split nodes: out = relu(carryL[g0] +
// sum_mid(carryF+carryL) + carryF[g1] + b). Deg-0 nodes: relu(b).
// ---------------------------------------------------------------------------
__global__ __launch_bounds__(256)
void fixup_kernel(const int* __restrict__ row_ptr,
                  const float* __restrict__ carryF,
                  const float* __restrict__ carryL,
                  const float* __restrict__ bias,
                  float* __restrict__ out) {
    const int tid  = blockIdx.x * 256 + threadIdx.x;
    const int node = tid >> 4;
    const int il   = tid & 15;
    if (node >= N_NODES) return;

    const int s = row_ptr[node];
    const int t = row_ptr[node + 1];
    const float4 b0 = *reinterpret_cast<const float4*>(bias + il * 8);
    const float4 b1 = *reinterpret_cast<const float4*>(bias + il * 8 + 4);

    float a[8];
    if (s == t) {
#pragma unroll
        for (int j = 0; j < 8; ++j) a[j] = 0.f;
    } else {
        const int g0 = s / K_EDGES;
        const int g1 = (t - 1) / K_EDGES;
        if (g0 == g1) return;  // fully interior, written by gather
        const float* pl = carryL + (size_t)g0 * 128 + il * 8;
        const float* pf = carryF + (size_t)g1 * 128 + il * 8;
#pragma unroll
        for (int j = 0; j < 8; ++j) a[j] = pl[j] + pf[j];
        for (int g = g0 + 1; g < g1; ++g) {  // essentially never executes
            const float* mf = carryF + (size_t)g * 128 + il * 8;
            const float* ml = carryL + (size_t)g * 128 + il * 8;
#pragma unroll
            for (int j = 0; j < 8; ++j) a[j] += mf[j] + ml[j];
        }
    }

    f32x4 r0, r1;
    r0[0] = a[0] + b0.x; r0[1] = a[1] + b0.y;
    r0[2] = a[2] + b0.z; r0[3] = a[3] + b0.w;
    r1[0] = a[4] + b1.x; r1[1] = a[5] + b1.y;
    r1[2] = a[6] + b1.z; r1[3] = a[7] + b1.w;
#pragma unroll
    for (int i = 0; i < 4; ++i) {
        r0[i] = r0[i] > 0.f ? r0[i] : 0.f;
        r1[i] = r1[i] > 0.f ? r1[i] : 0.f;
    }
    float* op = out + (size_t)node * D + il * 8;
    *reinterpret_cast<f32x4*>(op)     = r0;
    *reinterpret_cast<f32x4*>(op + 4) = r1;
}

// ---------------------------------------------------------------------------
extern "C" void kernel_launch(void* const* d_in, const int* in_sizes, int n_in,
                              void* d_out, int out_size, void* d_ws,
                              size_t ws_size, hipStream_t stream) {
    const int*   edge_rows = (const int*)d_in[0];
    const int*   edge_cols = (const int*)d_in[1];
    const float* edge_vals = (const float*)d_in[2];
    const float* h         = (const float*)d_in[3];
    const float* W         = (const float*)d_in[4];
    const float* b         = (const float*)d_in[5];
    float*       out       = (float*)d_out;

    const int n_edges  = in_sizes[0];
    const int n_groups = (n_edges + K_EDGES - 1) / K_EDGES;  // 12500

    // ws: [Wfrag 32K|pad64K][row_ptr 400K|pad512K][scales 400K|pad512K]
    //     [carryF 6.4M][carryL 6.4M][Gq 12.8M]   total ~26.7MB
    const size_t OFF_RP = 64 * 1024;
    const size_t OFF_SC = OFF_RP + 512 * 1024;
    const size_t OFF_CF = OFF_SC + 512 * 1024;
    const size_t OFF_CL = OFF_CF + (size_t)n_groups * 128 * sizeof(float);
    const size_t OFF_GQ = OFF_CL + (size_t)n_groups * 128 * sizeof(float);

    ushort_t* Wfrag   = (ushort_t*)d_ws;
    int*      row_ptr = (int*)((char*)d_ws + OFF_RP);
    float*    scales  = (float*)((char*)d_ws + OFF_SC);
    float*    carryF  = (float*)((char*)d_ws + OFF_CF);
    float*    carryL  = (float*)((char*)d_ws + OFF_CL);
    uchar_t*  Gq      = (uchar_t*)((char*)d_ws + OFF_GQ);

    build_wfrag_kernel<<<32, 64, 0, stream>>>(W, Wfrag);

    build_rowptr_boundary_kernel<<<(n_edges + 255) / 256, 256, 0, stream>>>(
        edge_rows, row_ptr, n_edges);

    const int n_tiles     = N_NODES / 16;  // 6250
    const int gemm_blocks = (n_tiles + 3) / 4;
    gemm_Gq_kernel<<<gemm_blocks, 256, 0, stream>>>(h, Wfrag, Gq, scales);

    const int gather_blocks = (n_groups * 16 + 255) / 256;  // 782
    gconv_gather_eb_kernel<<<gather_blocks, 256, 0, stream>>>(
        edge_rows, edge_cols, edge_vals, Gq, scales, b, out, carryF, carryL,
        n_edges, n_groups);

    const int fixup_blocks = (N_NODES * 16 + 255) / 256;  // 6250
    fixup_kernel<<<fixup_blocks, 256, 0, stream>>>(row_ptr, carryF, carryL, b,
                                                   out);
}

// Round 10
// 128.963 us; speedup vs baseline: 3.9211x; 1.0216x over previous
//
#include <hip/hip_runtime.h>

#define N_NODES 100000
#define D 128

typedef unsigned short ushort_t;
typedef unsigned char uchar_t;
typedef __attribute__((ext_vector_type(8))) short short8;
typedef __attribute__((ext_vector_type(4))) float f32x4;
typedef __attribute__((ext_vector_type(4))) int i32x4;

// round-to-nearest-even f32 -> bf16 bits (finite inputs)
__device__ __forceinline__ unsigned f2bf(float x) {
    unsigned u = __float_as_uint(x);
    return (u + 0x7fffu + ((u >> 16) & 1u)) >> 16;
}

// ---------------------------------------------------------------------------
// Kernel 1: W -> MFMA A-fragment-ordered bf16 (Wfrag).
// ---------------------------------------------------------------------------
__global__ __launch_bounds__(64)
void build_wfrag_kernel(const float* __restrict__ W,
                        ushort_t* __restrict__ Wfrag) {
    const int t  = blockIdx.x;      // 0..31 = jt*4 + kt
    const int jt = t >> 2, kt = t & 3;
    const int l  = threadIdx.x;
    const float* src = W + (size_t)(jt * 16 + (l & 15)) * D + kt * 32 + (l >> 4) * 8;
    const float4 p0 = *reinterpret_cast<const float4*>(src);
    const float4 p1 = *reinterpret_cast<const float4*>(src + 4);
    uint4 o;
    o.x = f2bf(p0.x) | (f2bf(p0.y) << 16);
    o.y = f2bf(p0.z) | (f2bf(p0.w) << 16);
    o.z = f2bf(p1.x) | (f2bf(p1.y) << 16);
    o.w = f2bf(p1.z) | (f2bf(p1.w) << 16);
    *reinterpret_cast<uint4*>(Wfrag + ((size_t)t * 64 + l) * 8) = o;
}

// ---------------------------------------------------------------------------
// Kernel 2: row_ptr by boundary detection on the SORTED edge_rows.
// ---------------------------------------------------------------------------
__global__ __launch_bounds__(256)
void build_rowptr_boundary_kernel(const int* __restrict__ rows,
                                  int* __restrict__ row_ptr, int n_edges) {
    const int e = blockIdx.x * 256 + threadIdx.x;
    if (e >= n_edges) return;
    const int r0 = rows[e];
    if (e == 0) {
        for (int r = 0; r <= r0; ++r) row_ptr[r] = 0;
    }
    if (e + 1 < n_edges) {
        const int r1 = rows[e + 1];
        for (int r = r0 + 1; r <= r1; ++r) row_ptr[r] = e + 1;
    } else {
        for (int r = r0 + 1; r <= N_NODES; ++r) row_ptr[r] = n_edges;
    }
}

// ---------------------------------------------------------------------------
// Kernel 3: G = H @ W^T via MFMA, quantized per-node to uint8 (+128 bias):
//   Gq[node][j] = round(g/s) + 128, s = scales[node] = rowmax|g|/127.
// ---------------------------------------------------------------------------
__global__ __launch_bounds__(256)
void gemm_Gq_kernel(const float* __restrict__ h,
                    const ushort_t* __restrict__ Wfrag,
                    uchar_t* __restrict__ Gq,
                    float* __restrict__ scales) {
    const int wave = threadIdx.x >> 6;
    const int l    = threadIdx.x & 63;
    const int tile = blockIdx.x * 4 + wave;
    if (tile >= N_NODES / 16) return;
    const int n0   = tile * 16;
    const int lrow = l & 15;
    const int lk   = l >> 4;

    union { short8 v; ushort_t u[8]; } bfrag[4];
    const float* hp = h + (size_t)(n0 + lrow) * D + lk * 8;
#pragma unroll
    for (int kt = 0; kt < 4; ++kt) {
        const float4 q0 = *reinterpret_cast<const float4*>(hp + kt * 32);
        const float4 q1 = *reinterpret_cast<const float4*>(hp + kt * 32 + 4);
        bfrag[kt].u[0] = (ushort_t)f2bf(q0.x);
        bfrag[kt].u[1] = (ushort_t)f2bf(q0.y);
        bfrag[kt].u[2] = (ushort_t)f2bf(q0.z);
        bfrag[kt].u[3] = (ushort_t)f2bf(q0.w);
        bfrag[kt].u[4] = (ushort_t)f2bf(q1.x);
        bfrag[kt].u[5] = (ushort_t)f2bf(q1.y);
        bfrag[kt].u[6] = (ushort_t)f2bf(q1.z);
        bfrag[kt].u[7] = (ushort_t)f2bf(q1.w);
    }

    const uint4* wf = reinterpret_cast<const uint4*>(Wfrag) + l;
    f32x4 acc[8];
#pragma unroll
    for (int jt = 0; jt < 8; ++jt) {
        acc[jt] = (f32x4){0.f, 0.f, 0.f, 0.f};
#pragma unroll
        for (int kt = 0; kt < 4; ++kt) {
            union { uint4 q; short8 v; } af;
            af.q = wf[(jt * 4 + kt) * 64];
            acc[jt] = __builtin_amdgcn_mfma_f32_16x16x32_bf16(
                af.v, bfrag[kt].v, acc[jt], 0, 0, 0);
        }
    }

    float amax = 0.f;
#pragma unroll
    for (int jt = 0; jt < 8; ++jt) {
#pragma unroll
        for (int r = 0; r < 4; ++r) amax = fmaxf(amax, fabsf(acc[jt][r]));
    }
    amax = fmaxf(amax, __shfl_xor(amax, 16));
    amax = fmaxf(amax, __shfl_xor(amax, 32));
    const float s   = amax > 0.f ? amax * (1.f / 127.f) : 1.f;
    const float inv = amax > 0.f ? 127.f / amax : 0.f;

#pragma unroll
    for (int jt = 0; jt < 8; ++jt) {
        const unsigned q0 = (unsigned)((int)rintf(acc[jt][0] * inv) + 128);
        const unsigned q1 = (unsigned)((int)rintf(acc[jt][1] * inv) + 128);
        const unsigned q2 = (unsigned)((int)rintf(acc[jt][2] * inv) + 128);
        const unsigned q3 = (unsigned)((int)rintf(acc[jt][3] * inv) + 128);
        const unsigned pk = q0 | (q1 << 8) | (q2 << 16) | (q3 << 24);
        *reinterpret_cast<unsigned*>(
            Gq + (size_t)(n0 + lrow) * D + jt * 16 + lk * 4) = pk;
    }
    if (l < 16) scales[n0 + l] = s;
}

// ---------------------------------------------------------------------------
// Kernel 4: edge-balanced gather, chunk size K = 1<<log2k (runtime).
// Each 16-lane group owns edges [grp<<log2k, +K). Interior row-runs -> out;
// boundary-clipped runs -> carryF/carryL[grp]. Carry slots always written.
// ---------------------------------------------------------------------------
__device__ __forceinline__ void accq(float* a, float& vsum, float vs, uint2 g) {
    a[0] += vs * (float)(g.x & 0xffu);
    a[1] += vs * (float)((g.x >> 8) & 0xffu);
    a[2] += vs * (float)((g.x >> 16) & 0xffu);
    a[3] += vs * (float)(g.x >> 24);
    a[4] += vs * (float)(g.y & 0xffu);
    a[5] += vs * (float)((g.y >> 8) & 0xffu);
    a[6] += vs * (float)((g.y >> 16) & 0xffu);
    a[7] += vs * (float)(g.y >> 24);
    vsum += vs;
}

__device__ __forceinline__ void flush_run(
    int node, bool finalClipR, bool clippedL,
    bool& firstRun, bool& wroteF, bool& wroteL,
    float* a, float& vsum, int grp, int il,
    float* __restrict__ out, float* __restrict__ carryF,
    float* __restrict__ carryL, float4 b0, float4 b1) {
    const float corr = 128.f * vsum;
    const bool cL = firstRun && clippedL;
    if (cL || finalClipR) {
        float4 p0, p1;
        p0.x = a[0] - corr; p0.y = a[1] - corr;
        p0.z = a[2] - corr; p0.w = a[3] - corr;
        p1.x = a[4] - corr; p1.y = a[5] - corr;
        p1.z = a[6] - corr; p1.w = a[7] - corr;
        float* dst = (cL ? carryF : carryL) + (size_t)grp * 128 + il * 8;
        *reinterpret_cast<float4*>(dst)     = p0;
        *reinterpret_cast<float4*>(dst + 4) = p1;
        if (cL) wroteF = true; else wroteL = true;
    } else {
        f32x4 r0, r1;
        r0[0] = a[0] - corr + b0.x; r0[1] = a[1] - corr + b0.y;
        r0[2] = a[2] - corr + b0.z; r0[3] = a[3] - corr + b0.w;
        r1[0] = a[4] - corr + b1.x; r1[1] = a[5] - corr + b1.y;
        r1[2] = a[6] - corr + b1.z; r1[3] = a[7] - corr + b1.w;
#pragma unroll
        for (int i = 0; i < 4; ++i) {
            r0[i] = r0[i] > 0.f ? r0[i] : 0.f;
            r1[i] = r1[i] > 0.f ? r1[i] : 0.f;
        }
        float* op = out + (size_t)node * D + il * 8;
        *reinterpret_cast<f32x4*>(op)     = r0;
        *reinterpret_cast<f32x4*>(op + 4) = r1;
    }
    firstRun = false;
#pragma unroll
    for (int j = 0; j < 8; ++j) a[j] = 0.f;
    vsum = 0.f;
}

__global__ __launch_bounds__(256)
void gconv_gather_eb_kernel(const int* __restrict__ rows,
                            const int* __restrict__ cols,
                            const float* __restrict__ vals,
                            const uchar_t* __restrict__ Gq,
                            const float* __restrict__ scales,
                            const float* __restrict__ bias,
                            float* __restrict__ out,
                            float* __restrict__ carryF,
                            float* __restrict__ carryL,
                            int n_edges, int n_groups, int log2k) {
    const int tid = blockIdx.x * 256 + threadIdx.x;
    const int grp = tid >> 4;
    const int il  = tid & 15;
    if (grp >= n_groups) return;

    const int e0 = grp << log2k;
    const int e1 = min(n_edges, e0 + (1 << log2k));
    const uchar_t* gp = Gq + il * 8;
    const float4 b0 = *reinterpret_cast<const float4*>(bias + il * 8);
    const float4 b1 = *reinterpret_cast<const float4*>(bias + il * 8 + 4);

    int cur = rows[e0];
    const bool clippedL = (grp > 0) && (rows[e0 - 1] == cur);
    bool firstRun = true, wroteF = false, wroteL = false;

    float a[8];
#pragma unroll
    for (int j = 0; j < 8; ++j) a[j] = 0.f;
    float vsum = 0.f;

    int e = e0;
    for (; e + 8 <= e1; e += 8) {
        const i32x4 ra = *reinterpret_cast<const i32x4*>(rows + e);
        const i32x4 rb = *reinterpret_cast<const i32x4*>(rows + e + 4);
        const i32x4 ca = *reinterpret_cast<const i32x4*>(cols + e);
        const i32x4 cb = *reinterpret_cast<const i32x4*>(cols + e + 4);
        const f32x4 va = *reinterpret_cast<const f32x4*>(vals + e);
        const f32x4 vb = *reinterpret_cast<const f32x4*>(vals + e + 4);
        const int r[8] = {ra[0], ra[1], ra[2], ra[3], rb[0], rb[1], rb[2], rb[3]};
        const int c[8] = {ca[0], ca[1], ca[2], ca[3], cb[0], cb[1], cb[2], cb[3]};
        const float v[8] = {va[0], va[1], va[2], va[3], vb[0], vb[1], vb[2], vb[3]};
        float s[8];
#pragma unroll
        for (int i = 0; i < 8; ++i) s[i] = scales[c[i]];
        uint2 g[8];
#pragma unroll
        for (int i = 0; i < 8; ++i)
            g[i] = *reinterpret_cast<const uint2*>(gp + (size_t)c[i] * D);
#pragma unroll
        for (int i = 0; i < 8; ++i) {
            if (r[i] != cur) {
                flush_run(cur, false, clippedL, firstRun, wroteF, wroteL,
                          a, vsum, grp, il, out, carryF, carryL, b0, b1);
                cur = r[i];
            }
            accq(a, vsum, v[i] * s[i], g[i]);
        }
    }
    for (; e < e1; ++e) {  // tail (last group only)
        const int r_ = rows[e];
        const int c_ = cols[e];
        if (r_ != cur) {
            flush_run(cur, false, clippedL, firstRun, wroteF, wroteL,
                      a, vsum, grp, il, out, carryF, carryL, b0, b1);
            cur = r_;
        }
        const uint2 g_ = *reinterpret_cast<const uint2*>(gp + (size_t)c_ * D);
        accq(a, vsum, vals[e] * scales[c_], g_);
    }

    const bool clipR = (e1 < n_edges) && (rows[e1] == cur);
    flush_run(cur, clipR, clippedL, firstRun, wroteF, wroteL,
              a, vsum, grp, il, out, carryF, carryL, b0, b1);

    const f32x4 z = {0.f, 0.f, 0.f, 0.f};
    if (!wroteF) {
        float* dst = carryF + (size_t)grp * 128 + il * 8;
        *reinterpret_cast<f32x4*>(dst)     = z;
        *reinterpret_cast<f32x4*>(dst + 4) = z;
    }
    if (!wroteL) {
        float* dst = carryL + (size_t)grp * 128 + il * 8;
        *reinterpret_cast<f32x4*>(dst)     = z;
        *reinterpret_cast<f32x4*>(dst + 4) = z;
    }
}

// ---------------------------------------------------------------------------
// Kernel 5: fixup. Boundary-split nodes: out = relu(carryL[g0] +
// sum_mid(carryF+carryL) + carryF[g1] + b). Deg-0 nodes: relu(b).
// ---------------------------------------------------------------------------
__global__ __launch_bounds__(256)
void fixup_kernel(const int* __restrict__ row_ptr,
                  const float* __restrict__ carryF,
                  const float* __restrict__ carryL,
                  const float* __restrict__ bias,
                  float* __restrict__ out, int log2k) {
    const int tid  = blockIdx.x * 256 + threadIdx.x;
    const int node = tid >> 4;
    const int il   = tid & 15;
    if (node >= N_NODES) return;

    const int s = row_ptr[node];
    const int t = row_ptr[node + 1];
    const float4 b0 = *reinterpret_cast<const float4*>(bias + il * 8);
    const float4 b1 = *reinterpret_cast<const float4*>(bias + il * 8 + 4);

    float a[8];
    if (s == t) {
#pragma unroll
        for (int j = 0; j < 8; ++j) a[j] = 0.f;
    } else {
        const int g0 = s >> log2k;
        const int g1 = (t - 1) >> log2k;
        if (g0 == g1) return;  // fully interior, written by gather
        const float* pl = carryL + (size_t)g0 * 128 + il * 8;
        const float* pf = carryF + (size_t)g1 * 128 + il * 8;
#pragma unroll
        for (int j = 0; j < 8; ++j) a[j] = pl[j] + pf[j];
        for (int g = g0 + 1; g < g1; ++g) {
            const float* mf = carryF + (size_t)g * 128 + il * 8;
            const float* ml = carryL + (size_t)g * 128 + il * 8;
#pragma unroll
            for (int j = 0; j < 8; ++j) a[j] += mf[j] + ml[j];
        }
    }

    f32x4 r0, r1;
    r0[0] = a[0] + b0.x; r0[1] = a[1] + b0.y;
    r0[2] = a[2] + b0.z; r0[3] = a[3] + b0.w;
    r1[0] = a[4] + b1.x; r1[1] = a[5] + b1.y;
    r1[2] = a[6] + b1.z; r1[3] = a[7] + b1.w;
#pragma unroll
    for (int i = 0; i < 4; ++i) {
        r0[i] = r0[i] > 0.f ? r0[i] : 0.f;
        r1[i] = r1[i] > 0.f ? r1[i] : 0.f;
    }
    float* op = out + (size_t)node * D + il * 8;
    *reinterpret_cast<f32x4*>(op)     = r0;
    *reinterpret_cast<f32x4*>(op + 4) = r1;
}

// ---------------------------------------------------------------------------
extern "C" void kernel_launch(void* const* d_in, const int* in_sizes, int n_in,
                              void* d_out, int out_size, void* d_ws,
                              size_t ws_size, hipStream_t stream) {
    const int*   edge_rows = (const int*)d_in[0];
    const int*   edge_cols = (const int*)d_in[1];
    const float* edge_vals = (const float*)d_in[2];
    const float* h         = (const float*)d_in[3];
    const float* W         = (const float*)d_in[4];
    const float* b         = (const float*)d_in[5];
    float*       out       = (float*)d_out;

    const int n_edges = in_sizes[0];

    // Pick smallest chunk K (max parallelism) whose carries fit ws_size.
    // ws: [Wfrag 32K|pad64K][row_ptr 400K|pad512K][scales 400K|pad512K]
    //     [carryF][carryL][Gq 12.8M]
    const size_t OFF_RP = 64 * 1024;
    const size_t OFF_SC = OFF_RP + 512 * 1024;
    const size_t OFF_CF = OFF_SC + 512 * 1024;
    const size_t GQ_SZ  = (size_t)N_NODES * D;

    int log2k = 8;
    for (int lk = 6; lk <= 8; ++lk) {
        const int ng = (n_edges + (1 << lk) - 1) >> lk;
        const size_t need = OFF_CF + 2 * (size_t)ng * 128 * sizeof(float) + GQ_SZ;
        if (need <= ws_size) { log2k = lk; break; }
    }
    const int n_groups = (n_edges + (1 << log2k) - 1) >> log2k;
    const size_t OFF_CL = OFF_CF + (size_t)n_groups * 128 * sizeof(float);
    const size_t OFF_GQ = OFF_CL + (size_t)n_groups * 128 * sizeof(float);

    ushort_t* Wfrag   = (ushort_t*)d_ws;
    int*      row_ptr = (int*)((char*)d_ws + OFF_RP);
    float*    scales  = (float*)((char*)d_ws + OFF_SC);
    float*    carryF  = (float*)((char*)d_ws + OFF_CF);
    float*    carryL  = (float*)((char*)d_ws + OFF_CL);
    uchar_t*  Gq      = (uchar_t*)((char*)d_ws + OFF_GQ);

    build_wfrag_kernel<<<32, 64, 0, stream>>>(W, Wfrag);

    build_rowptr_boundary_kernel<<<(n_edges + 255) / 256, 256, 0, stream>>>(
        edge_rows, row_ptr, n_edges);

    const int n_tiles     = N_NODES / 16;  // 6250
    const int gemm_blocks = (n_tiles + 3) / 4;
    gemm_Gq_kernel<<<gemm_blocks, 256, 0, stream>>>(h, Wfrag, Gq, scales);

    const int gather_blocks = (n_groups * 16 + 255) / 256;
    gconv_gather_eb_kernel<<<gather_blocks, 256, 0, stream>>>(
        edge_rows, edge_cols, edge_vals, Gq, scales, b, out, carryF, carryL,
        n_edges, n_groups, log2k);

    const int fixup_blocks = (N_NODES * 16 + 255) / 256;  // 6250
    fixup_kernel<<<fixup_blocks, 256, 0, stream>>>(row_ptr, carryF, carryL, b,
                                                   out, log2k);
}